// Round 6
// baseline (2741.989 us; speedup 1.0000x reference)
//
#include <hip/hip_runtime.h>

#define TPB 512

// ---- workspace layout (floats) ----
#define OFF_PE      0        // 6 x [40x32] card_emb @ {q,k,v}^T for h2t,t2h
#define OFF_HPROJ   7680     // [61][64]  wt[j][d] = w_hproj[d][j]
#define OFF_POSB    11584    // [40][64]  b_hproj[d] + pos[i][d]
#define OFF_ENCQ    14144    // [64][64]  wt[j][d] = enc_win[d][j]      (rows 0..63)
#define OFF_ENCK    18240    // [64][64]  rows 64..127
#define OFF_ENCV    22336    // [64][64]  rows 128..191
#define OFF_ENCOUT  26432    // [64][64]
#define OFF_FF1     30528    // [64][128] wt[j][f] = w_ff1[f][j]
#define OFF_FF2     38720    // [128][64] wt[f][d] = w_ff2[d][f]
#define OFF_MERGE   46912    // [224][64]
#define OFF_STATS   61248    // [383][64]
#define OFF_COMB    85760    // [224][256]
#define OFF_H2TWO   143104   // [32][32]  wt[e][d] = h2t_wout[d][e]
#define OFF_T2HWO   144128   // [32][32]
#define WS_TOTAL    145152

struct P {
  const float *obs, *seat, *ce, *wch, *bch, *wcc, *bcc,
    *h2t_win, *h2t_bin, *h2t_wout, *h2t_bout,
    *t2h_win, *t2h_bin, *t2h_wout, *t2h_bout,
    *w_merge, *b_merge, *w_hproj, *b_hproj, *pos,
    *enc_win, *enc_bin, *enc_wout, *enc_bout,
    *ln1_g, *ln1_b, *w_ff1, *b_ff1, *w_ff2, *b_ff2, *ln2_g, *ln2_b,
    *w_stats, *b_stats, *w_seat, *b_seat, *w_comb, *b_comb;
  const float* ws;
  float* out;
};

// One-off prep: pe + all weight transposes into d_ws. Batch-independent.
__global__ void prep_kernel(P p, float* ws) {
  int t = blockIdx.x * blockDim.x + threadIdx.x;
  if (t >= WS_TOTAL) return;
  if (t < OFF_HPROJ) {                       // pe
    int arr = t / 1280, rem = t - arr * 1280;
    int i = rem >> 5, d = rem & 31;
    const float* win = (arr < 3) ? p.h2t_win : p.t2h_win;
    const float* wr = win + ((arr % 3) * 32 + d) * 32;
    const float* cr = p.ce + i * 32;
    float acc = 0.f;
    #pragma unroll
    for (int j = 0; j < 32; ++j) acc += cr[j] * wr[j];
    ws[t] = acc;
  } else if (t < OFF_POSB) {
    int r = t - OFF_HPROJ; int j = r >> 6, d = r & 63;
    ws[t] = p.w_hproj[d * 61 + j];
  } else if (t < OFF_ENCQ) {
    int r = t - OFF_POSB; int d = r & 63;
    ws[t] = p.b_hproj[d] + p.pos[r];
  } else if (t < OFF_ENCK) {
    int r = t - OFF_ENCQ; int j = r >> 6, d = r & 63;
    ws[t] = p.enc_win[d * 64 + j];
  } else if (t < OFF_ENCV) {
    int r = t - OFF_ENCK; int j = r >> 6, d = r & 63;
    ws[t] = p.enc_win[(64 + d) * 64 + j];
  } else if (t < OFF_ENCOUT) {
    int r = t - OFF_ENCV; int j = r >> 6, d = r & 63;
    ws[t] = p.enc_win[(128 + d) * 64 + j];
  } else if (t < OFF_FF1) {
    int r = t - OFF_ENCOUT; int j = r >> 6, d = r & 63;
    ws[t] = p.enc_wout[d * 64 + j];
  } else if (t < OFF_FF2) {
    int r = t - OFF_FF1; int j = r >> 7, f = r & 127;
    ws[t] = p.w_ff1[f * 64 + j];
  } else if (t < OFF_MERGE) {
    int r = t - OFF_FF2; int f = r >> 6, d = r & 63;
    ws[t] = p.w_ff2[d * 128 + f];
  } else if (t < OFF_STATS) {
    int r = t - OFF_MERGE; int j = r >> 6, d = r & 63;
    ws[t] = p.w_merge[d * 224 + j];
  } else if (t < OFF_COMB) {
    int r = t - OFF_STATS; int j = r >> 6, d = r & 63;
    ws[t] = p.w_stats[d * 383 + j];
  } else if (t < OFF_H2TWO) {
    int r = t - OFF_COMB; int j = r >> 8, d = r & 255;
    ws[t] = p.w_comb[d * 224 + j];
  } else if (t < OFF_T2HWO) {
    int r = t - OFF_H2TWO; int e = r >> 5, d = r & 31;
    ws[t] = p.h2t_wout[d * 32 + e];
  } else {
    int r = t - OFF_T2HWO; int e = r >> 5, d = r & 31;
    ws[t] = p.t2h_wout[d * 32 + e];
  }
}

// launch_bounds 2nd arg: measured on this toolchain as min BLOCKS/CU
// (R5 evidence: (512,6) -> 12 waves/EU -> VGPR cap 40 -> GB-scale spill).
// (512,3): 3 blocks/CU (LDS-capped anyway) -> VGPR cap ~85 under blocks-
// semantics, ~170 under waves-semantics; no spill either way.
__global__ __launch_bounds__(TPB, 3) void enc_row(P p) {
  const int row = blockIdx.x;
  const int tid = threadIdx.x;
  const int lane = tid & 63, wq = tid >> 6;

  __shared__ float s_ht[165];  // hand_table region of obs
  __shared__ float sA[2560];   // hseq -> x(post-LN1) -> x2(post-LN2)
  __shared__ float sB[2560];   // enc K -> pre-LN1 -> ff[0:2560]
  __shared__ float sC[2560];   // enc V -> ff[2560:5120]
  __shared__ float sD[2624];   // enc Q^T (stride 41) -> attn O^T -> pre-LN2 (linear)
  __shared__ float s_om[64];   // masked-mean accum: h2t[0:32], t2h[32:64]
  __shared__ float s_sm[224];  // set_merged
  __shared__ float s_cb[256];  // combined (224 used; stats accumulated at 128..191)
  __shared__ int   s_cnt[2];   // hand count, table count

  const float* orow = p.obs + (size_t)row * 2988;
  const float* ws = p.ws;

  // ---- S1: stage + small set features + accum inits + presence counts ----
  if (tid < 165) s_ht[tid] = orow[tid];
  if (tid < 32) {
    float a = 0.f;
    for (int i = 0; i < 40; ++i) a += orow[i] * p.ce[i * 32 + tid];
    s_sm[tid] = a;                                     // hand_feat
  } else if (tid < 64) {
    int d = tid - 32; float a = 0.f;
    for (int i = 0; i < 40; ++i) a += orow[43 + i] * p.ce[i * 32 + d];
    s_sm[32 + d] = a;                                  // table_feat
  } else if (tid < 96) {
    int d = tid - 64; float a = 0.f;
    for (int i = 0; i < 40; ++i) a += orow[83 + i] * p.ce[i * 32 + d];
    s_sm[64 + d] = a;                                  // cap0_feat
  } else if (tid < 128) {
    int d = tid - 96; float a = 0.f;
    for (int i = 0; i < 40; ++i) a += orow[123 + i] * p.ce[i * 32 + d];
    s_sm[96 + d] = a;                                  // cap1_feat
  } else if (tid < 144) {
    int d = tid - 128;
    float a = p.bch[d];
    for (int j = 0; j < 3; ++j) a += orow[40 + j] * p.wch[d * 3 + j];
    s_sm[192 + d] = fmaxf(a, 0.f);                     // other_cnt_feat
  } else if (tid < 160) {
    int d = tid - 144;
    float a = p.bcc[d];
    for (int j = 0; j < 2; ++j) a += orow[163 + j] * p.wcc[d * 2 + j];
    s_sm[208 + d] = fmaxf(a, 0.f);                     // cap_cnt_feat
  }
  if (tid >= 192 && tid < 256) s_om[tid - 192] = 0.f;
  if (tid >= 256 && tid < 320) s_cb[128 + tid - 256] = p.b_stats[tid - 256];  // stats accum init
  if (tid == 320) {
    int c = 0; for (int i = 0; i < 40; ++i) c += (orow[i] > 0.5f);
    s_cnt[0] = c;
  } else if (tid == 321) {
    int c = 0; for (int i = 0; i < 40; ++i) c += (orow[43 + i] > 0.5f);
    s_cnt[1] = c;
  }
  __syncthreads();
  #define OB(i) s_ht[i]

  // ---- R3: card attention (640 pair-split, parity-split score regs) + hseq proj + stats ----
  for (int t = tid; t < 1376; t += TPB) {
    if (t < 640) {
      int eh = t & 1, q = t >> 1;
      int a = q / 160, r = q - a * 160;
      int h = r / 40, i = r - h * 40;
      int qoff = a ? 43 : 0, koff = a ? 0 : 43;
      const float* Cq = ws + OFF_PE + a * 3840;
      const float* Ck = Cq + 1280;
      const float* Cv = Cq + 2560;
      const float* bin = a ? p.t2h_bin : p.h2t_bin;
      const int e0 = h * 8 + eh * 4;
      float qm = OB(qoff + i);
      float4 cq = *(const float4*)(Cq + i * 32 + e0);
      float4 bq = *(const float4*)(bin + e0);
      float4 bk = *(const float4*)(bin + 32 + e0);
      float q0 = qm * cq.x + bq.x, q1 = qm * cq.y + bq.y;
      float q2 = qm * cq.z + bq.z, q3 = qm * cq.w + bq.w;
      const float scale = 0.35355339059327373f;  // 1/sqrt(8)
      float sreg[20];                             // own-parity scores only
      float mx = -1e30f;
      #pragma unroll
      for (int j = 0; j < 40; ++j) {
        float km = OB(koff + j);
        float part = 0.f;
        if (km > 0.5f) {
          float4 ck = *(const float4*)(Ck + j * 32 + e0);
          part = q0 * (km * ck.x + bk.x) + q1 * (km * ck.y + bk.y)
               + q2 * (km * ck.z + bk.z) + q3 * (km * ck.w + bk.w);
        }
        float full = part + __shfl_xor(part, 1, 64);   // combine half-dots
        float s = (km > 0.5f) ? full * scale : -1e30f;
        if ((j & 1) == eh) sreg[j >> 1] = s;           // store own parity
        mx = fmaxf(mx, s);
      }
      float den = 0.f;
      float o0 = 0.f, o1 = 0.f, o2 = 0.f, o3 = 0.f;
      #pragma unroll
      for (int j = 0; j < 40; ++j) {
        float val = sreg[j >> 1];
        float oth = __shfl_xor(val, 1, 64);            // partner's same-slot score
        float sj = ((j & 1) == eh) ? val : oth;
        float km = OB(koff + j);
        if (km > 0.5f) {
          float pj = __expf(sj - mx);
          den += pj;
          float pk = pj * km;
          float4 cv = *(const float4*)(Cv + j * 32 + e0);
          o0 += pk * cv.x; o1 += pk * cv.y; o2 += pk * cv.z; o3 += pk * cv.w;
        }
      }
      float inv = 1.f / den;  // den==0 only if all keys masked; result gated by cnt later
      if (qm > 0.5f) {        // masked_mean sums only present queries
        float4 bv = *(const float4*)(bin + 64 + e0);
        atomicAdd(&s_om[a * 32 + e0 + 0], o0 * inv + bv.x);
        atomicAdd(&s_om[a * 32 + e0 + 1], o1 * inv + bv.y);
        atomicAdd(&s_om[a * 32 + e0 + 2], o2 * inv + bv.z);
        atomicAdd(&s_om[a * 32 + e0 + 3], o3 * inv + bv.w);
      }
    } else if (t < 1280) {
      // hseq[i][d0..d0+3] = hist[i] . w_hproj + b + pos
      int r = t - 640;
      int i = r >> 4, d0 = (r & 15) << 2;
      float4 acc = *(const float4*)(ws + OFF_POSB + i * 64 + d0);
      const float* hist = orow + 165 + i * 61;
      const float* wt = ws + OFF_HPROJ + d0;
      for (int j = 0; j < 60; j += 2) {
        float a0 = hist[j], a1 = hist[j + 1];
        float4 w0 = *(const float4*)(wt + j * 64);
        float4 w1 = *(const float4*)(wt + (j + 1) * 64);
        acc.x += a0 * w0.x + a1 * w1.x;
        acc.y += a0 * w0.y + a1 * w1.y;
        acc.z += a0 * w0.z + a1 * w1.z;
        acc.w += a0 * w0.w + a1 * w1.w;
      }
      {
        float a0 = hist[60];
        float4 w0 = *(const float4*)(wt + 60 * 64);
        acc.x += a0 * w0.x; acc.y += a0 * w0.y; acc.z += a0 * w0.z; acc.w += a0 * w0.w;
      }
      *(float4*)(sA + i * 64 + d0) = acc;
    } else {
      // stats partial: chunk c covers j in [c*64, min(383, c*64+64))
      int r = t - 1280;
      int c = r >> 4, d0 = (r & 15) << 2;
      int j0 = c * 64, j1 = (c == 5) ? 383 : j0 + 64;
      const float* st = orow + 2605;
      const float* wt = ws + OFF_STATS + d0;
      float x0 = 0.f, x1 = 0.f, x2 = 0.f, x3 = 0.f;
      for (int j = j0; j < j1; ++j) {
        float a0 = st[j];
        float4 w = *(const float4*)(wt + j * 64);
        x0 += a0 * w.x; x1 += a0 * w.y; x2 += a0 * w.z; x3 += a0 * w.w;
      }
      atomicAdd(&s_cb[128 + d0 + 0], x0);
      atomicAdd(&s_cb[128 + d0 + 1], x1);
      atomicAdd(&s_cb[128 + d0 + 2], x2);
      atomicAdd(&s_cb[128 + d0 + 3], x3);
    }
  }
  __syncthreads();

  // ---- R4: enc Q/K/V (1920, d-tile 4) + attn-mean feats (16, d-tile 4) ----
  for (int t = tid; t < 1936; t += TPB) {
    if (t < 1920) {
      int which = t / 640, r = t - which * 640;
      int i = r >> 4, d0 = (r & 15) << 2;
      const float* wt = ws + (which == 0 ? OFF_ENCQ : (which == 1 ? OFF_ENCK : OFF_ENCV)) + d0;
      const float* arow = sA + (i << 6);
      float4 acc = *(const float4*)(p.enc_bin + (which << 6) + d0);
      for (int j = 0; j < 64; j += 4) {
        float4 a4 = *(const float4*)(arow + j);
        float4 w0 = *(const float4*)(wt + j * 64);
        float4 w1 = *(const float4*)(wt + (j + 1) * 64);
        float4 w2 = *(const float4*)(wt + (j + 2) * 64);
        float4 w3 = *(const float4*)(wt + (j + 3) * 64);
        acc.x += a4.x * w0.x + a4.y * w1.x + a4.z * w2.x + a4.w * w3.x;
        acc.y += a4.x * w0.y + a4.y * w1.y + a4.z * w2.y + a4.w * w3.y;
        acc.z += a4.x * w0.z + a4.y * w1.z + a4.z * w2.z + a4.w * w3.z;
        acc.w += a4.x * w0.w + a4.y * w1.w + a4.z * w2.w + a4.w * w3.w;
      }
      if (which == 0) {       // Q^T, stride 41 (conflict-free columns)
        sD[(d0 + 0) * 41 + i] = acc.x;
        sD[(d0 + 1) * 41 + i] = acc.y;
        sD[(d0 + 2) * 41 + i] = acc.z;
        sD[(d0 + 3) * 41 + i] = acc.w;
      } else {
        *(float4*)(((which == 1) ? sB : sC) + (i << 6) + d0) = acc;
      }
    } else {
      int r = t - 1920;
      int a = r >> 3, d0 = (r & 7) << 2;
      int ch = s_cnt[0], ct = s_cnt[1];
      float4 v = make_float4(0.f, 0.f, 0.f, 0.f);
      if (ch > 0 && ct > 0) {
        float ic = 1.f / (float)(a ? ct : ch);
        const float* wt = ws + (a ? OFF_T2HWO : OFF_H2TWO) + d0;
        const float* om = s_om + a * 32;
        v = *(const float4*)((a ? p.t2h_bout : p.h2t_bout) + d0);
        for (int e = 0; e < 32; ++e) {
          float oe = om[e] * ic;
          float4 w = *(const float4*)(wt + e * 32);
          v.x += oe * w.x; v.y += oe * w.y; v.z += oe * w.z; v.w += oe * w.w;
        }
      }
      *(float4*)(s_sm + 128 + a * 32 + d0) = v;
    }
  }
  __syncthreads();

  // ---- R5: encoder attention (320 pair-split, parity-split scores) + set_feat ----
  if (tid < 320) {
    int eh = tid & 1, q = tid >> 1;
    int h = q / 40, i = q - h * 40;
    const int e0 = h * 16 + eh * 8;
    float q8[8];
    #pragma unroll
    for (int e = 0; e < 8; ++e) q8[e] = sD[(e0 + e) * 41 + i];
    float sreg[20];
    float mx = -1e30f;
    #pragma unroll
    for (int j = 0; j < 40; ++j) {
      const float* kr = sB + (j << 6) + e0;
      float4 k0 = *(const float4*)kr;
      float4 k1 = *(const float4*)(kr + 4);
      float part = q8[0] * k0.x + q8[1] * k0.y + q8[2] * k0.z + q8[3] * k0.w
                 + q8[4] * k1.x + q8[5] * k1.y + q8[6] * k1.z + q8[7] * k1.w;
      float s = (part + __shfl_xor(part, 1, 64)) * 0.25f;  // 1/sqrt(16)
      if ((j & 1) == eh) sreg[j >> 1] = s;
      mx = fmaxf(mx, s);
    }
    float den = 0.f;
    float o8[8];
    #pragma unroll
    for (int e = 0; e < 8; ++e) o8[e] = 0.f;
    #pragma unroll
    for (int j = 0; j < 40; ++j) {
      float val = sreg[j >> 1];
      float oth = __shfl_xor(val, 1, 64);
      float sj = ((j & 1) == eh) ? val : oth;
      float pj = __expf(sj - mx);
      den += pj;
      const float* vr = sC + (j << 6) + e0;
      float4 v0 = *(const float4*)vr;
      float4 v1 = *(const float4*)(vr + 4);
      o8[0] += pj * v0.x; o8[1] += pj * v0.y; o8[2] += pj * v0.z; o8[3] += pj * v0.w;
      o8[4] += pj * v1.x; o8[5] += pj * v1.y; o8[6] += pj * v1.z; o8[7] += pj * v1.w;
    }
    float inv = 1.f / den;
    #pragma unroll
    for (int e = 0; e < 8; ++e) sD[(e0 + e) * 41 + i] = o8[e] * inv;  // O^T, own slots
  } else if (tid < 336) {
    int d0 = (tid - 320) << 2;
    const float* wt = ws + OFF_MERGE + d0;
    float4 acc = *(const float4*)(p.b_merge + d0);
    for (int j = 0; j < 224; j += 4) {
      float4 a4 = *(const float4*)(s_sm + j);
      float4 w0 = *(const float4*)(wt + j * 64);
      float4 w1 = *(const float4*)(wt + (j + 1) * 64);
      float4 w2 = *(const float4*)(wt + (j + 2) * 64);
      float4 w3 = *(const float4*)(wt + (j + 3) * 64);
      acc.x += a4.x * w0.x + a4.y * w1.x + a4.z * w2.x + a4.w * w3.x;
      acc.y += a4.x * w0.y + a4.y * w1.y + a4.z * w2.y + a4.w * w3.y;
      acc.z += a4.x * w0.z + a4.y * w1.z + a4.z * w2.z + a4.w * w3.z;
      acc.w += a4.x * w0.w + a4.y * w1.w + a4.z * w2.w + a4.w * w3.w;
    }
    acc.x = fmaxf(acc.x, 0.f); acc.y = fmaxf(acc.y, 0.f);
    acc.z = fmaxf(acc.z, 0.f); acc.w = fmaxf(acc.w, 0.f);
    *(float4*)(s_cb + d0) = acc;                       // set_feat
  }
  __syncthreads();

  // ---- R6: attn out-proj + residual -> pre-LN1 (i-tile 4 x col d) ----
  for (int t = tid; t < 640; t += TPB) {
    int d = t & 63, i0 = (t >> 6) << 2;
    const float* wt = ws + OFF_ENCOUT + d;
    float bo = p.enc_bout[d];
    float a0 = sA[(i0 + 0) * 64 + d] + bo;
    float a1 = sA[(i0 + 1) * 64 + d] + bo;
    float a2 = sA[(i0 + 2) * 64 + d] + bo;
    float a3 = sA[(i0 + 3) * 64 + d] + bo;
    for (int j = 0; j < 64; j += 2) {
      const float* oc = sD + j * 41 + i0;
      float w0 = wt[j * 64], w1 = wt[(j + 1) * 64];
      const float* oc1 = oc + 41;
      a0 += oc[0] * w0 + oc1[0] * w1;
      a1 += oc[1] * w0 + oc1[1] * w1;
      a2 += oc[2] * w0 + oc1[2] * w1;
      a3 += oc[3] * w0 + oc1[3] * w1;
    }
    sB[(i0 + 0) * 64 + d] = a0;
    sB[(i0 + 1) * 64 + d] = a1;
    sB[(i0 + 2) * 64 + d] = a2;
    sB[(i0 + 3) * 64 + d] = a3;
  }
  __syncthreads();

  // ---- R7: LN1 (wave-parallel) -> sA ----
  {
    float g = p.ln1_g[lane], b = p.ln1_b[lane];
    for (int i = wq; i < 40; i += 8) {
      float x = sB[(i << 6) + lane];
      float s = x;
      #pragma unroll
      for (int off = 32; off; off >>= 1) s += __shfl_xor(s, off, 64);
      float m = s * 0.015625f;
      float xm = x - m;
      float v = xm * xm;
      #pragma unroll
      for (int off = 32; off; off >>= 1) v += __shfl_xor(v, off, 64);
      float rs = rsqrtf(v * 0.015625f + 1e-5f);
      sA[(i << 6) + lane] = xm * rs * g + b;
    }
  }
  __syncthreads();

  // ---- R8: FF1 (relu), f-tile 4 -> sB|sC ----
  for (int t = tid; t < 1280; t += TPB) {
    int i = t >> 5, f0 = (t & 31) << 2;
    const float* wt = ws + OFF_FF1 + f0;
    const float* arow = sA + (i << 6);
    float4 acc = *(const float4*)(p.b_ff1 + f0);
    for (int j = 0; j < 64; j += 4) {
      float4 a4 = *(const float4*)(arow + j);
      float4 w0 = *(const float4*)(wt + j * 128);
      float4 w1 = *(const float4*)(wt + (j + 1) * 128);
      float4 w2 = *(const float4*)(wt + (j + 2) * 128);
      float4 w3 = *(const float4*)(wt + (j + 3) * 128);
      acc.x += a4.x * w0.x + a4.y * w1.x + a4.z * w2.x + a4.w * w3.x;
      acc.y += a4.x * w0.y + a4.y * w1.y + a4.z * w2.y + a4.w * w3.y;
      acc.z += a4.x * w0.z + a4.y * w1.z + a4.z * w2.z + a4.w * w3.z;
      acc.w += a4.x * w0.w + a4.y * w1.w + a4.z * w2.w + a4.w * w3.w;
    }
    acc.x = fmaxf(acc.x, 0.f); acc.y = fmaxf(acc.y, 0.f);
    acc.z = fmaxf(acc.z, 0.f); acc.w = fmaxf(acc.w, 0.f);
    float* dst = (i < 20) ? (sB + (i << 7)) : (sC + ((i - 20) << 7));
    *(float4*)(dst + f0) = acc;
  }
  __syncthreads();

  // ---- R9: FF2 + residual -> pre-LN2 (sD linear), d-tile 4 ----
  for (int t = tid; t < 640; t += TPB) {
    int i = t >> 4, d0 = (t & 15) << 2;
    const float* wt = ws + OFF_FF2 + d0;
    const float* F = (i < 20) ? (sB + (i << 7)) : (sC + ((i - 20) << 7));
    float4 res = *(const float4*)(sA + (i << 6) + d0);
    float4 bb = *(const float4*)(p.b_ff2 + d0);
    float4 acc = make_float4(res.x + bb.x, res.y + bb.y, res.z + bb.z, res.w + bb.w);
    for (int f = 0; f < 128; f += 4) {
      float4 a4 = *(const float4*)(F + f);
      float4 w0 = *(const float4*)(wt + f * 64);
      float4 w1 = *(const float4*)(wt + (f + 1) * 64);
      float4 w2 = *(const float4*)(wt + (f + 2) * 64);
      float4 w3 = *(const float4*)(wt + (f + 3) * 64);
      acc.x += a4.x * w0.x + a4.y * w1.x + a4.z * w2.x + a4.w * w3.x;
      acc.y += a4.x * w0.y + a4.y * w1.y + a4.z * w2.y + a4.w * w3.y;
      acc.z += a4.x * w0.z + a4.y * w1.z + a4.z * w2.z + a4.w * w3.z;
      acc.w += a4.x * w0.w + a4.y * w1.w + a4.z * w2.w + a4.w * w3.w;
    }
    *(float4*)(sD + (i << 6) + d0) = acc;
  }
  __syncthreads();

  // ---- R10: LN2 (wave-parallel) -> sA ----
  {
    float g = p.ln2_g[lane], b = p.ln2_b[lane];
    for (int i = wq; i < 40; i += 8) {
      float x = sD[(i << 6) + lane];
      float s = x;
      #pragma unroll
      for (int off = 32; off; off >>= 1) s += __shfl_xor(s, off, 64);
      float m = s * 0.015625f;
      float xm = x - m;
      float v = xm * xm;
      #pragma unroll
      for (int off = 32; off; off >>= 1) v += __shfl_xor(v, off, 64);
      float rs = rsqrtf(v * 0.015625f + 1e-5f);
      sA[(i << 6) + lane] = xm * rs * g + b;
    }
  }
  __syncthreads();

  // ---- R11: hist mean + stats relu + seat_feat ----
  if (tid < 64) {
    float a = 0.f;
    for (int i = 0; i < 40; ++i) a += sA[(i << 6) + tid];
    s_cb[64 + tid] = a * 0.025f;                       // hist_feat
    s_cb[128 + tid] = fmaxf(s_cb[128 + tid], 0.f);     // stats relu (accumulated in R3)
  } else if (tid < 96) {
    int d = tid - 64;
    const float* sv = p.seat + (size_t)row * 6;
    float acc = p.b_seat[d];
    for (int j = 0; j < 6; ++j) acc += sv[j] * p.w_seat[d * 6 + j];
    s_cb[192 + d] = fmaxf(acc, 0.f);                   // seat_feat
  }
  __syncthreads();

  // ---- R12: final 224 -> 256 matvec + relu ----
  if (tid < 256) {
    const float* wt = ws + OFF_COMB + tid;
    float acc = p.b_comb[tid];
    for (int j = 0; j < 224; j += 4) {
      float4 a4 = *(const float4*)(s_cb + j);
      acc += a4.x * wt[j * 256] + a4.y * wt[(j + 1) * 256]
           + a4.z * wt[(j + 2) * 256] + a4.w * wt[(j + 3) * 256];
    }
    p.out[(size_t)row * 256 + tid] = fmaxf(acc, 0.f);
  }
  #undef OB
}

extern "C" void kernel_launch(void* const* d_in, const int* in_sizes, int n_in,
                              void* d_out, int out_size, void* d_ws, size_t ws_size,
                              hipStream_t stream) {
  typedef const float* F;
  P p;
  p.obs      = (F)d_in[0];
  p.seat     = (F)d_in[1];
  p.ce       = (F)d_in[2];
  p.wch      = (F)d_in[3];
  p.bch      = (F)d_in[4];
  p.wcc      = (F)d_in[5];
  p.bcc      = (F)d_in[6];
  p.h2t_win  = (F)d_in[7];
  p.h2t_bin  = (F)d_in[8];
  p.h2t_wout = (F)d_in[9];
  p.h2t_bout = (F)d_in[10];
  p.t2h_win  = (F)d_in[11];
  p.t2h_bin  = (F)d_in[12];
  p.t2h_wout = (F)d_in[13];
  p.t2h_bout = (F)d_in[14];
  p.w_merge  = (F)d_in[15];
  p.b_merge  = (F)d_in[16];
  p.w_hproj  = (F)d_in[17];
  p.b_hproj  = (F)d_in[18];
  p.pos      = (F)d_in[19];
  p.enc_win  = (F)d_in[20];
  p.enc_bin  = (F)d_in[21];
  p.enc_wout = (F)d_in[22];
  p.enc_bout = (F)d_in[23];
  p.ln1_g    = (F)d_in[24];
  p.ln1_b    = (F)d_in[25];
  p.w_ff1    = (F)d_in[26];
  p.b_ff1    = (F)d_in[27];
  p.w_ff2    = (F)d_in[28];
  p.b_ff2    = (F)d_in[29];
  p.ln2_g    = (F)d_in[30];
  p.ln2_b    = (F)d_in[31];
  p.w_stats  = (F)d_in[32];
  p.b_stats  = (F)d_in[33];
  p.w_seat   = (F)d_in[34];
  p.b_seat   = (F)d_in[35];
  p.w_comb   = (F)d_in[36];
  p.b_comb   = (F)d_in[37];
  p.ws  = (const float*)d_ws;
  p.out = (float*)d_out;

  const int Bn = in_sizes[0] / 2988;
  hipLaunchKernelGGL(prep_kernel, dim3((WS_TOTAL + 255) / 256), dim3(256), 0, stream,
                     p, (float*)d_ws);
  hipLaunchKernelGGL(enc_row, dim3(Bn), dim3(TPB), 0, stream, p);
}

// Round 7
// 2019.731 us; speedup vs baseline: 1.3576x; 1.3576x over previous
//
#include <hip/hip_runtime.h>

#define TPB 512

// ---- workspace layout (floats) ----
#define OFF_PE      0        // 6 x [40x32] card_emb @ {q,k,v}^T for h2t,t2h
#define OFF_HPROJ   7680     // [61][64]  wt[j][d] = w_hproj[d][j]
#define OFF_POSB    11584    // [40][64]  b_hproj[d] + pos[i][d]
#define OFF_ENCQ    14144    // [64][64]  wt[j][d] = enc_win[d][j]      (rows 0..63)
#define OFF_ENCK    18240    // [64][64]  rows 64..127
#define OFF_ENCV    22336    // [64][64]  rows 128..191
#define OFF_ENCOUT  26432    // [64][64]
#define OFF_FF1     30528    // [64][128] wt[j][f] = w_ff1[f][j]
#define OFF_FF2     38720    // [128][64] wt[f][d] = w_ff2[d][f]
#define OFF_MERGE   46912    // [224][64]
#define OFF_STATS   61248    // [383][64]
#define OFF_COMB    85760    // [224][256]
#define OFF_H2TWO   143104   // [32][32]  wt[e][d] = h2t_wout[d][e]
#define OFF_T2HWO   144128   // [32][32]
#define WS_TOTAL    145152

struct P {
  const float *obs, *seat, *ce, *wch, *bch, *wcc, *bcc,
    *h2t_win, *h2t_bin, *h2t_wout, *h2t_bout,
    *t2h_win, *t2h_bin, *t2h_wout, *t2h_bout,
    *w_merge, *b_merge, *w_hproj, *b_hproj, *pos,
    *enc_win, *enc_bin, *enc_wout, *enc_bout,
    *ln1_g, *ln1_b, *w_ff1, *b_ff1, *w_ff2, *b_ff2, *ln2_g, *ln2_b,
    *w_stats, *b_stats, *w_seat, *b_seat, *w_comb, *b_comb;
  const float* ws;
  float* out;
};

// One-off prep: pe + all weight transposes into d_ws. Batch-independent.
__global__ void prep_kernel(P p, float* ws) {
  int t = blockIdx.x * blockDim.x + threadIdx.x;
  if (t >= WS_TOTAL) return;
  if (t < OFF_HPROJ) {                       // pe
    int arr = t / 1280, rem = t - arr * 1280;
    int i = rem >> 5, d = rem & 31;
    const float* win = (arr < 3) ? p.h2t_win : p.t2h_win;
    const float* wr = win + ((arr % 3) * 32 + d) * 32;
    const float* cr = p.ce + i * 32;
    float acc = 0.f;
    #pragma unroll
    for (int j = 0; j < 32; ++j) acc += cr[j] * wr[j];
    ws[t] = acc;
  } else if (t < OFF_POSB) {
    int r = t - OFF_HPROJ; int j = r >> 6, d = r & 63;
    ws[t] = p.w_hproj[d * 61 + j];
  } else if (t < OFF_ENCQ) {
    int r = t - OFF_POSB; int d = r & 63;
    ws[t] = p.b_hproj[d] + p.pos[r];
  } else if (t < OFF_ENCK) {
    int r = t - OFF_ENCQ; int j = r >> 6, d = r & 63;
    ws[t] = p.enc_win[d * 64 + j];
  } else if (t < OFF_ENCV) {
    int r = t - OFF_ENCK; int j = r >> 6, d = r & 63;
    ws[t] = p.enc_win[(64 + d) * 64 + j];
  } else if (t < OFF_ENCOUT) {
    int r = t - OFF_ENCV; int j = r >> 6, d = r & 63;
    ws[t] = p.enc_win[(128 + d) * 64 + j];
  } else if (t < OFF_FF1) {
    int r = t - OFF_ENCOUT; int j = r >> 6, d = r & 63;
    ws[t] = p.enc_wout[d * 64 + j];
  } else if (t < OFF_FF2) {
    int r = t - OFF_FF1; int j = r >> 7, f = r & 127;
    ws[t] = p.w_ff1[f * 64 + j];
  } else if (t < OFF_MERGE) {
    int r = t - OFF_FF2; int f = r >> 6, d = r & 63;
    ws[t] = p.w_ff2[d * 128 + f];
  } else if (t < OFF_STATS) {
    int r = t - OFF_MERGE; int j = r >> 6, d = r & 63;
    ws[t] = p.w_merge[d * 224 + j];
  } else if (t < OFF_COMB) {
    int r = t - OFF_STATS; int j = r >> 6, d = r & 63;
    ws[t] = p.w_stats[d * 383 + j];
  } else if (t < OFF_H2TWO) {
    int r = t - OFF_COMB; int j = r >> 8, d = r & 255;
    ws[t] = p.w_comb[d * 224 + j];
  } else if (t < OFF_T2HWO) {
    int r = t - OFF_H2TWO; int e = r >> 5, d = r & 31;
    ws[t] = p.h2t_wout[d * 32 + e];
  } else {
    int r = t - OFF_T2HWO; int e = r >> 5, d = r & 31;
    ws[t] = p.t2h_wout[d * 32 + e];
  }
}

// launch_bounds 2nd arg measured as min BLOCKS/CU on this toolchain:
// (512,6)->VGPR cap 40, (512,3)->cap 84 (=512/(blocks*8waves/4EU)).
// (512,3): 3 blocks/CU (LDS caps at 3 anyway). Attention uses recompute-dot
// online softmax so live state stays ~30 regs -> no spill under the 84 cap.
__global__ __launch_bounds__(TPB, 3) void enc_row(P p) {
  const int row = blockIdx.x;
  const int tid = threadIdx.x;
  const int lane = tid & 63, wq = tid >> 6;

  __shared__ float s_ht[165];  // hand_table region of obs
  __shared__ float sA[2560];   // hseq -> x(post-LN1) -> x2(post-LN2)
  __shared__ float sB[2560];   // enc K -> pre-LN1 -> ff[0:2560]
  __shared__ float sC[2560];   // enc V -> ff[2560:5120]
  __shared__ float sD[2624];   // enc Q^T (stride 41) -> attn O^T -> pre-LN2 (linear)
  __shared__ float s_om[64];   // masked-mean accum: h2t[0:32], t2h[32:64]
  __shared__ float s_sm[224];  // set_merged
  __shared__ float s_cb[256];  // combined (224 used; stats accumulated at 128..191)
  __shared__ int   s_cnt[2];   // hand count, table count

  const float* orow = p.obs + (size_t)row * 2988;
  const float* ws = p.ws;

  // ---- S1: stage + small set features + accum inits + presence counts ----
  if (tid < 165) s_ht[tid] = orow[tid];
  if (tid < 32) {
    float a = 0.f;
    for (int i = 0; i < 40; ++i) a += orow[i] * p.ce[i * 32 + tid];
    s_sm[tid] = a;                                     // hand_feat
  } else if (tid < 64) {
    int d = tid - 32; float a = 0.f;
    for (int i = 0; i < 40; ++i) a += orow[43 + i] * p.ce[i * 32 + d];
    s_sm[32 + d] = a;                                  // table_feat
  } else if (tid < 96) {
    int d = tid - 64; float a = 0.f;
    for (int i = 0; i < 40; ++i) a += orow[83 + i] * p.ce[i * 32 + d];
    s_sm[64 + d] = a;                                  // cap0_feat
  } else if (tid < 128) {
    int d = tid - 96; float a = 0.f;
    for (int i = 0; i < 40; ++i) a += orow[123 + i] * p.ce[i * 32 + d];
    s_sm[96 + d] = a;                                  // cap1_feat
  } else if (tid < 144) {
    int d = tid - 128;
    float a = p.bch[d];
    for (int j = 0; j < 3; ++j) a += orow[40 + j] * p.wch[d * 3 + j];
    s_sm[192 + d] = fmaxf(a, 0.f);                     // other_cnt_feat
  } else if (tid < 160) {
    int d = tid - 144;
    float a = p.bcc[d];
    for (int j = 0; j < 2; ++j) a += orow[163 + j] * p.wcc[d * 2 + j];
    s_sm[208 + d] = fmaxf(a, 0.f);                     // cap_cnt_feat
  }
  if (tid >= 192 && tid < 256) s_om[tid - 192] = 0.f;
  if (tid >= 256 && tid < 320) s_cb[128 + tid - 256] = p.b_stats[tid - 256];  // stats accum init
  if (tid == 320) {
    int c = 0; for (int i = 0; i < 40; ++i) c += (orow[i] > 0.5f);
    s_cnt[0] = c;
  } else if (tid == 321) {
    int c = 0; for (int i = 0; i < 40; ++i) c += (orow[43 + i] > 0.5f);
    s_cnt[1] = c;
  }
  __syncthreads();
  #define OB(i) s_ht[i]

  // ---- R3: card attention (640 pair-split, recompute-dot softmax) + hseq proj + stats ----
  for (int t = tid; t < 1376; t += TPB) {
    if (t < 640) {
      int eh = t & 1, q = t >> 1;
      int a = q / 160, r = q - a * 160;
      int h = r / 40, i = r - h * 40;
      int qoff = a ? 43 : 0, koff = a ? 0 : 43;
      const float* Cq = ws + OFF_PE + a * 3840;
      const float* Ck = Cq + 1280;
      const float* Cv = Cq + 2560;
      const float* bin = a ? p.t2h_bin : p.h2t_bin;
      const int e0 = h * 8 + eh * 4;
      float qm = OB(qoff + i);
      float4 cq = *(const float4*)(Cq + i * 32 + e0);
      float4 bq = *(const float4*)(bin + e0);
      float4 bk = *(const float4*)(bin + 32 + e0);
      float q0 = qm * cq.x + bq.x, q1 = qm * cq.y + bq.y;
      float q2 = qm * cq.z + bq.z, q3 = qm * cq.w + bq.w;
      const float scale = 0.35355339059327373f;  // 1/sqrt(8)
      // pass 1: max only (km is pair-uniform -> shfl branch-safe)
      float mx = -1e30f;
      for (int j = 0; j < 40; ++j) {
        float km = OB(koff + j);
        float part = 0.f;
        if (km > 0.5f) {
          float4 ck = *(const float4*)(Ck + j * 32 + e0);
          part = q0 * (km * ck.x + bk.x) + q1 * (km * ck.y + bk.y)
               + q2 * (km * ck.z + bk.z) + q3 * (km * ck.w + bk.w);
        }
        float full = part + __shfl_xor(part, 1, 64);
        if (km > 0.5f) mx = fmaxf(mx, full * scale);
      }
      // pass 2: recompute dot, exp, denom, V-accumulate
      float den = 0.f;
      float o0 = 0.f, o1 = 0.f, o2 = 0.f, o3 = 0.f;
      for (int j = 0; j < 40; ++j) {
        float km = OB(koff + j);
        float part = 0.f;
        if (km > 0.5f) {
          float4 ck = *(const float4*)(Ck + j * 32 + e0);
          part = q0 * (km * ck.x + bk.x) + q1 * (km * ck.y + bk.y)
               + q2 * (km * ck.z + bk.z) + q3 * (km * ck.w + bk.w);
        }
        float full = part + __shfl_xor(part, 1, 64);
        if (km > 0.5f) {
          float pj = __expf(full * scale - mx);
          den += pj;
          float pk = pj * km;
          float4 cv = *(const float4*)(Cv + j * 32 + e0);
          o0 += pk * cv.x; o1 += pk * cv.y; o2 += pk * cv.z; o3 += pk * cv.w;
        }
      }
      float inv = 1.f / den;  // den==0 only if all keys masked; result gated by cnt later
      if (qm > 0.5f) {        // masked_mean sums only present queries
        float4 bv = *(const float4*)(bin + 64 + e0);
        atomicAdd(&s_om[a * 32 + e0 + 0], o0 * inv + bv.x);
        atomicAdd(&s_om[a * 32 + e0 + 1], o1 * inv + bv.y);
        atomicAdd(&s_om[a * 32 + e0 + 2], o2 * inv + bv.z);
        atomicAdd(&s_om[a * 32 + e0 + 3], o3 * inv + bv.w);
      }
    } else if (t < 1280) {
      // hseq[i][d0..d0+3] = hist[i] . w_hproj + b + pos
      int r = t - 640;
      int i = r >> 4, d0 = (r & 15) << 2;
      float4 acc = *(const float4*)(ws + OFF_POSB + i * 64 + d0);
      const float* hist = orow + 165 + i * 61;
      const float* wt = ws + OFF_HPROJ + d0;
      for (int j = 0; j < 60; j += 2) {
        float a0 = hist[j], a1 = hist[j + 1];
        float4 w0 = *(const float4*)(wt + j * 64);
        float4 w1 = *(const float4*)(wt + (j + 1) * 64);
        acc.x += a0 * w0.x + a1 * w1.x;
        acc.y += a0 * w0.y + a1 * w1.y;
        acc.z += a0 * w0.z + a1 * w1.z;
        acc.w += a0 * w0.w + a1 * w1.w;
      }
      {
        float a0 = hist[60];
        float4 w0 = *(const float4*)(wt + 60 * 64);
        acc.x += a0 * w0.x; acc.y += a0 * w0.y; acc.z += a0 * w0.z; acc.w += a0 * w0.w;
      }
      *(float4*)(sA + i * 64 + d0) = acc;
    } else {
      // stats partial: chunk c covers j in [c*64, min(383, c*64+64))
      int r = t - 1280;
      int c = r >> 4, d0 = (r & 15) << 2;
      int j0 = c * 64, j1 = (c == 5) ? 383 : j0 + 64;
      const float* st = orow + 2605;
      const float* wt = ws + OFF_STATS + d0;
      float x0 = 0.f, x1 = 0.f, x2 = 0.f, x3 = 0.f;
      for (int j = j0; j < j1; ++j) {
        float a0 = st[j];
        float4 w = *(const float4*)(wt + j * 64);
        x0 += a0 * w.x; x1 += a0 * w.y; x2 += a0 * w.z; x3 += a0 * w.w;
      }
      atomicAdd(&s_cb[128 + d0 + 0], x0);
      atomicAdd(&s_cb[128 + d0 + 1], x1);
      atomicAdd(&s_cb[128 + d0 + 2], x2);
      atomicAdd(&s_cb[128 + d0 + 3], x3);
    }
  }
  __syncthreads();

  // ---- R4: enc Q/K/V (1920, d-tile 4) + attn-mean feats (16, d-tile 4) ----
  for (int t = tid; t < 1936; t += TPB) {
    if (t < 1920) {
      int which = t / 640, r = t - which * 640;
      int i = r >> 4, d0 = (r & 15) << 2;
      const float* wt = ws + (which == 0 ? OFF_ENCQ : (which == 1 ? OFF_ENCK : OFF_ENCV)) + d0;
      const float* arow = sA + (i << 6);
      float4 acc = *(const float4*)(p.enc_bin + (which << 6) + d0);
      for (int j = 0; j < 64; j += 4) {
        float4 a4 = *(const float4*)(arow + j);
        float4 w0 = *(const float4*)(wt + j * 64);
        float4 w1 = *(const float4*)(wt + (j + 1) * 64);
        float4 w2 = *(const float4*)(wt + (j + 2) * 64);
        float4 w3 = *(const float4*)(wt + (j + 3) * 64);
        acc.x += a4.x * w0.x + a4.y * w1.x + a4.z * w2.x + a4.w * w3.x;
        acc.y += a4.x * w0.y + a4.y * w1.y + a4.z * w2.y + a4.w * w3.y;
        acc.z += a4.x * w0.z + a4.y * w1.z + a4.z * w2.z + a4.w * w3.z;
        acc.w += a4.x * w0.w + a4.y * w1.w + a4.z * w2.w + a4.w * w3.w;
      }
      if (which == 0) {       // Q^T, stride 41 (conflict-free columns)
        sD[(d0 + 0) * 41 + i] = acc.x;
        sD[(d0 + 1) * 41 + i] = acc.y;
        sD[(d0 + 2) * 41 + i] = acc.z;
        sD[(d0 + 3) * 41 + i] = acc.w;
      } else {
        *(float4*)(((which == 1) ? sB : sC) + (i << 6) + d0) = acc;
      }
    } else {
      int r = t - 1920;
      int a = r >> 3, d0 = (r & 7) << 2;
      int ch = s_cnt[0], ct = s_cnt[1];
      float4 v = make_float4(0.f, 0.f, 0.f, 0.f);
      if (ch > 0 && ct > 0) {
        float ic = 1.f / (float)(a ? ct : ch);
        const float* wt = ws + (a ? OFF_T2HWO : OFF_H2TWO) + d0;
        const float* om = s_om + a * 32;
        v = *(const float4*)((a ? p.t2h_bout : p.h2t_bout) + d0);
        for (int e = 0; e < 32; ++e) {
          float oe = om[e] * ic;
          float4 w = *(const float4*)(wt + e * 32);
          v.x += oe * w.x; v.y += oe * w.y; v.z += oe * w.z; v.w += oe * w.w;
        }
      }
      *(float4*)(s_sm + 128 + a * 32 + d0) = v;
    }
  }
  __syncthreads();

  // ---- R5: encoder attention (320 pair-split, recompute-dot softmax) + set_feat ----
  if (tid < 320) {
    int eh = tid & 1, q = tid >> 1;
    int h = q / 40, i = q - h * 40;
    const int e0 = h * 16 + eh * 8;
    float q8[8];
    #pragma unroll
    for (int e = 0; e < 8; ++e) q8[e] = sD[(e0 + e) * 41 + i];
    float mx = -1e30f;
    for (int j = 0; j < 40; ++j) {
      const float* kr = sB + (j << 6) + e0;
      float4 k0 = *(const float4*)kr;
      float4 k1 = *(const float4*)(kr + 4);
      float part = q8[0] * k0.x + q8[1] * k0.y + q8[2] * k0.z + q8[3] * k0.w
                 + q8[4] * k1.x + q8[5] * k1.y + q8[6] * k1.z + q8[7] * k1.w;
      float s = (part + __shfl_xor(part, 1, 64)) * 0.25f;  // 1/sqrt(16)
      mx = fmaxf(mx, s);
    }
    float den = 0.f;
    float o8[8];
    #pragma unroll
    for (int e = 0; e < 8; ++e) o8[e] = 0.f;
    for (int j = 0; j < 40; ++j) {
      const float* kr = sB + (j << 6) + e0;
      float4 k0 = *(const float4*)kr;
      float4 k1 = *(const float4*)(kr + 4);
      float part = q8[0] * k0.x + q8[1] * k0.y + q8[2] * k0.z + q8[3] * k0.w
                 + q8[4] * k1.x + q8[5] * k1.y + q8[6] * k1.z + q8[7] * k1.w;
      float s = (part + __shfl_xor(part, 1, 64)) * 0.25f;
      float pj = __expf(s - mx);
      den += pj;
      const float* vr = sC + (j << 6) + e0;
      float4 v0 = *(const float4*)vr;
      float4 v1 = *(const float4*)(vr + 4);
      o8[0] += pj * v0.x; o8[1] += pj * v0.y; o8[2] += pj * v0.z; o8[3] += pj * v0.w;
      o8[4] += pj * v1.x; o8[5] += pj * v1.y; o8[6] += pj * v1.z; o8[7] += pj * v1.w;
    }
    float inv = 1.f / den;
    #pragma unroll
    for (int e = 0; e < 8; ++e) sD[(e0 + e) * 41 + i] = o8[e] * inv;  // O^T, own slots
  } else if (tid < 336) {
    int d0 = (tid - 320) << 2;
    const float* wt = ws + OFF_MERGE + d0;
    float4 acc = *(const float4*)(p.b_merge + d0);
    for (int j = 0; j < 224; j += 4) {
      float4 a4 = *(const float4*)(s_sm + j);
      float4 w0 = *(const float4*)(wt + j * 64);
      float4 w1 = *(const float4*)(wt + (j + 1) * 64);
      float4 w2 = *(const float4*)(wt + (j + 2) * 64);
      float4 w3 = *(const float4*)(wt + (j + 3) * 64);
      acc.x += a4.x * w0.x + a4.y * w1.x + a4.z * w2.x + a4.w * w3.x;
      acc.y += a4.x * w0.y + a4.y * w1.y + a4.z * w2.y + a4.w * w3.y;
      acc.z += a4.x * w0.z + a4.y * w1.z + a4.z * w2.z + a4.w * w3.z;
      acc.w += a4.x * w0.w + a4.y * w1.w + a4.z * w2.w + a4.w * w3.w;
    }
    acc.x = fmaxf(acc.x, 0.f); acc.y = fmaxf(acc.y, 0.f);
    acc.z = fmaxf(acc.z, 0.f); acc.w = fmaxf(acc.w, 0.f);
    *(float4*)(s_cb + d0) = acc;                       // set_feat
  }
  __syncthreads();

  // ---- R6: attn out-proj + residual -> pre-LN1 (i-tile 4 x col d) ----
  for (int t = tid; t < 640; t += TPB) {
    int d = t & 63, i0 = (t >> 6) << 2;
    const float* wt = ws + OFF_ENCOUT + d;
    float bo = p.enc_bout[d];
    float a0 = sA[(i0 + 0) * 64 + d] + bo;
    float a1 = sA[(i0 + 1) * 64 + d] + bo;
    float a2 = sA[(i0 + 2) * 64 + d] + bo;
    float a3 = sA[(i0 + 3) * 64 + d] + bo;
    for (int j = 0; j < 64; j += 2) {
      const float* oc = sD + j * 41 + i0;
      float w0 = wt[j * 64], w1 = wt[(j + 1) * 64];
      const float* oc1 = oc + 41;
      a0 += oc[0] * w0 + oc1[0] * w1;
      a1 += oc[1] * w0 + oc1[1] * w1;
      a2 += oc[2] * w0 + oc1[2] * w1;
      a3 += oc[3] * w0 + oc1[3] * w1;
    }
    sB[(i0 + 0) * 64 + d] = a0;
    sB[(i0 + 1) * 64 + d] = a1;
    sB[(i0 + 2) * 64 + d] = a2;
    sB[(i0 + 3) * 64 + d] = a3;
  }
  __syncthreads();

  // ---- R7: LN1 (wave-parallel) -> sA ----
  {
    float g = p.ln1_g[lane], b = p.ln1_b[lane];
    for (int i = wq; i < 40; i += 8) {
      float x = sB[(i << 6) + lane];
      float s = x;
      #pragma unroll
      for (int off = 32; off; off >>= 1) s += __shfl_xor(s, off, 64);
      float m = s * 0.015625f;
      float xm = x - m;
      float v = xm * xm;
      #pragma unroll
      for (int off = 32; off; off >>= 1) v += __shfl_xor(v, off, 64);
      float rs = rsqrtf(v * 0.015625f + 1e-5f);
      sA[(i << 6) + lane] = xm * rs * g + b;
    }
  }
  __syncthreads();

  // ---- R8: FF1 (relu), f-tile 4 -> sB|sC ----
  for (int t = tid; t < 1280; t += TPB) {
    int i = t >> 5, f0 = (t & 31) << 2;
    const float* wt = ws + OFF_FF1 + f0;
    const float* arow = sA + (i << 6);
    float4 acc = *(const float4*)(p.b_ff1 + f0);
    for (int j = 0; j < 64; j += 4) {
      float4 a4 = *(const float4*)(arow + j);
      float4 w0 = *(const float4*)(wt + j * 128);
      float4 w1 = *(const float4*)(wt + (j + 1) * 128);
      float4 w2 = *(const float4*)(wt + (j + 2) * 128);
      float4 w3 = *(const float4*)(wt + (j + 3) * 128);
      acc.x += a4.x * w0.x + a4.y * w1.x + a4.z * w2.x + a4.w * w3.x;
      acc.y += a4.x * w0.y + a4.y * w1.y + a4.z * w2.y + a4.w * w3.y;
      acc.z += a4.x * w0.z + a4.y * w1.z + a4.z * w2.z + a4.w * w3.z;
      acc.w += a4.x * w0.w + a4.y * w1.w + a4.z * w2.w + a4.w * w3.w;
    }
    acc.x = fmaxf(acc.x, 0.f); acc.y = fmaxf(acc.y, 0.f);
    acc.z = fmaxf(acc.z, 0.f); acc.w = fmaxf(acc.w, 0.f);
    float* dst = (i < 20) ? (sB + (i << 7)) : (sC + ((i - 20) << 7));
    *(float4*)(dst + f0) = acc;
  }
  __syncthreads();

  // ---- R9: FF2 + residual -> pre-LN2 (sD linear), d-tile 4 ----
  for (int t = tid; t < 640; t += TPB) {
    int i = t >> 4, d0 = (t & 15) << 2;
    const float* wt = ws + OFF_FF2 + d0;
    const float* F = (i < 20) ? (sB + (i << 7)) : (sC + ((i - 20) << 7));
    float4 res = *(const float4*)(sA + (i << 6) + d0);
    float4 bb = *(const float4*)(p.b_ff2 + d0);
    float4 acc = make_float4(res.x + bb.x, res.y + bb.y, res.z + bb.z, res.w + bb.w);
    for (int f = 0; f < 128; f += 4) {
      float4 a4 = *(const float4*)(F + f);
      float4 w0 = *(const float4*)(wt + f * 64);
      float4 w1 = *(const float4*)(wt + (f + 1) * 64);
      float4 w2 = *(const float4*)(wt + (f + 2) * 64);
      float4 w3 = *(const float4*)(wt + (f + 3) * 64);
      acc.x += a4.x * w0.x + a4.y * w1.x + a4.z * w2.x + a4.w * w3.x;
      acc.y += a4.x * w0.y + a4.y * w1.y + a4.z * w2.y + a4.w * w3.y;
      acc.z += a4.x * w0.z + a4.y * w1.z + a4.z * w2.z + a4.w * w3.z;
      acc.w += a4.x * w0.w + a4.y * w1.w + a4.z * w2.w + a4.w * w3.w;
    }
    *(float4*)(sD + (i << 6) + d0) = acc;
  }
  __syncthreads();

  // ---- R10: LN2 (wave-parallel) -> sA ----
  {
    float g = p.ln2_g[lane], b = p.ln2_b[lane];
    for (int i = wq; i < 40; i += 8) {
      float x = sD[(i << 6) + lane];
      float s = x;
      #pragma unroll
      for (int off = 32; off; off >>= 1) s += __shfl_xor(s, off, 64);
      float m = s * 0.015625f;
      float xm = x - m;
      float v = xm * xm;
      #pragma unroll
      for (int off = 32; off; off >>= 1) v += __shfl_xor(v, off, 64);
      float rs = rsqrtf(v * 0.015625f + 1e-5f);
      sA[(i << 6) + lane] = xm * rs * g + b;
    }
  }
  __syncthreads();

  // ---- R11: hist mean + stats relu + seat_feat ----
  if (tid < 64) {
    float a = 0.f;
    for (int i = 0; i < 40; ++i) a += sA[(i << 6) + tid];
    s_cb[64 + tid] = a * 0.025f;                       // hist_feat
    s_cb[128 + tid] = fmaxf(s_cb[128 + tid], 0.f);     // stats relu (accumulated in R3)
  } else if (tid < 96) {
    int d = tid - 64;
    const float* sv = p.seat + (size_t)row * 6;
    float acc = p.b_seat[d];
    for (int j = 0; j < 6; ++j) acc += sv[j] * p.w_seat[d * 6 + j];
    s_cb[192 + d] = fmaxf(acc, 0.f);                   // seat_feat
  }
  __syncthreads();

  // ---- R12: final 224 -> 256 matvec + relu ----
  if (tid < 256) {
    const float* wt = ws + OFF_COMB + tid;
    float acc = p.b_comb[tid];
    for (int j = 0; j < 224; j += 4) {
      float4 a4 = *(const float4*)(s_cb + j);
      acc += a4.x * wt[j * 256] + a4.y * wt[(j + 1) * 256]
           + a4.z * wt[(j + 2) * 256] + a4.w * wt[(j + 3) * 256];
    }
    p.out[(size_t)row * 256 + tid] = fmaxf(acc, 0.f);
  }
  #undef OB
}

extern "C" void kernel_launch(void* const* d_in, const int* in_sizes, int n_in,
                              void* d_out, int out_size, void* d_ws, size_t ws_size,
                              hipStream_t stream) {
  typedef const float* F;
  P p;
  p.obs      = (F)d_in[0];
  p.seat     = (F)d_in[1];
  p.ce       = (F)d_in[2];
  p.wch      = (F)d_in[3];
  p.bch      = (F)d_in[4];
  p.wcc      = (F)d_in[5];
  p.bcc      = (F)d_in[6];
  p.h2t_win  = (F)d_in[7];
  p.h2t_bin  = (F)d_in[8];
  p.h2t_wout = (F)d_in[9];
  p.h2t_bout = (F)d_in[10];
  p.t2h_win  = (F)d_in[11];
  p.t2h_bin  = (F)d_in[12];
  p.t2h_wout = (F)d_in[13];
  p.t2h_bout = (F)d_in[14];
  p.w_merge  = (F)d_in[15];
  p.b_merge  = (F)d_in[16];
  p.w_hproj  = (F)d_in[17];
  p.b_hproj  = (F)d_in[18];
  p.pos      = (F)d_in[19];
  p.enc_win  = (F)d_in[20];
  p.enc_bin  = (F)d_in[21];
  p.enc_wout = (F)d_in[22];
  p.enc_bout = (F)d_in[23];
  p.ln1_g    = (F)d_in[24];
  p.ln1_b    = (F)d_in[25];
  p.w_ff1    = (F)d_in[26];
  p.b_ff1    = (F)d_in[27];
  p.w_ff2    = (F)d_in[28];
  p.b_ff2    = (F)d_in[29];
  p.ln2_g    = (F)d_in[30];
  p.ln2_b    = (F)d_in[31];
  p.w_stats  = (F)d_in[32];
  p.b_stats  = (F)d_in[33];
  p.w_seat   = (F)d_in[34];
  p.b_seat   = (F)d_in[35];
  p.w_comb   = (F)d_in[36];
  p.b_comb   = (F)d_in[37];
  p.ws  = (const float*)d_ws;
  p.out = (float*)d_out;

  const int Bn = in_sizes[0] / 2988;
  hipLaunchKernelGGL(prep_kernel, dim3((WS_TOTAL + 255) / 256), dim3(256), 0, stream,
                     p, (float*)d_ws);
  hipLaunchKernelGGL(enc_row, dim3(Bn), dim3(TPB), 0, stream, p);
}

// Round 8
// 1489.836 us; speedup vs baseline: 1.8405x; 1.3557x over previous
//
#include <hip/hip_runtime.h>

#define TPB 512

// ---- workspace layout (floats) ----
#define OFF_PE      0        // 6 x [40x32] card_emb @ {q,k,v}^T for h2t,t2h
#define OFF_HPROJ   7680     // [61][64]  wt[j][d] = w_hproj[d][j]
#define OFF_POSB    11584    // [40][64]  b_hproj[d] + pos[i][d]
#define OFF_ENCQ    14144    // [64][64]  wt[j][d] = enc_win[d][j]      (rows 0..63)
#define OFF_ENCK    18240    // [64][64]  rows 64..127
#define OFF_ENCV    22336    // [64][64]  rows 128..191
#define OFF_ENCOUT  26432    // [64][64]
#define OFF_FF1     30528    // [64][128] wt[j][f] = w_ff1[f][j]
#define OFF_FF2     38720    // [128][64] wt[f][d] = w_ff2[d][f]
#define OFF_MERGE   46912    // [224][64]
#define OFF_STATS   61248    // [383][64]
#define OFF_COMB    85760    // [224][256]
#define OFF_H2TWO   143104   // [32][32]  wt[e][d] = h2t_wout[d][e]
#define OFF_T2HWO   144128   // [32][32]
#define WS_TOTAL    145152

struct P {
  const float *obs, *seat, *ce, *wch, *bch, *wcc, *bcc,
    *h2t_win, *h2t_bin, *h2t_wout, *h2t_bout,
    *t2h_win, *t2h_bin, *t2h_wout, *t2h_bout,
    *w_merge, *b_merge, *w_hproj, *b_hproj, *pos,
    *enc_win, *enc_bin, *enc_wout, *enc_bout,
    *ln1_g, *ln1_b, *w_ff1, *b_ff1, *w_ff2, *b_ff2, *ln2_g, *ln2_b,
    *w_stats, *b_stats, *w_seat, *b_seat, *w_comb, *b_comb;
  const float* ws;
  float* out;
};

// One-off prep: pe + all weight transposes into d_ws. Batch-independent.
__global__ void prep_kernel(P p, float* ws) {
  int t = blockIdx.x * blockDim.x + threadIdx.x;
  if (t >= WS_TOTAL) return;
  if (t < OFF_HPROJ) {                       // pe
    int arr = t / 1280, rem = t - arr * 1280;
    int i = rem >> 5, d = rem & 31;
    const float* win = (arr < 3) ? p.h2t_win : p.t2h_win;
    const float* wr = win + ((arr % 3) * 32 + d) * 32;
    const float* cr = p.ce + i * 32;
    float acc = 0.f;
    #pragma unroll
    for (int j = 0; j < 32; ++j) acc += cr[j] * wr[j];
    ws[t] = acc;
  } else if (t < OFF_POSB) {
    int r = t - OFF_HPROJ; int j = r >> 6, d = r & 63;
    ws[t] = p.w_hproj[d * 61 + j];
  } else if (t < OFF_ENCQ) {
    int r = t - OFF_POSB; int d = r & 63;
    ws[t] = p.b_hproj[d] + p.pos[r];
  } else if (t < OFF_ENCK) {
    int r = t - OFF_ENCQ; int j = r >> 6, d = r & 63;
    ws[t] = p.enc_win[d * 64 + j];
  } else if (t < OFF_ENCV) {
    int r = t - OFF_ENCK; int j = r >> 6, d = r & 63;
    ws[t] = p.enc_win[(64 + d) * 64 + j];
  } else if (t < OFF_ENCOUT) {
    int r = t - OFF_ENCV; int j = r >> 6, d = r & 63;
    ws[t] = p.enc_win[(128 + d) * 64 + j];
  } else if (t < OFF_FF1) {
    int r = t - OFF_ENCOUT; int j = r >> 6, d = r & 63;
    ws[t] = p.enc_wout[d * 64 + j];
  } else if (t < OFF_FF2) {
    int r = t - OFF_FF1; int j = r >> 7, f = r & 127;
    ws[t] = p.w_ff1[f * 64 + j];
  } else if (t < OFF_MERGE) {
    int r = t - OFF_FF2; int f = r >> 6, d = r & 63;
    ws[t] = p.w_ff2[d * 128 + f];
  } else if (t < OFF_STATS) {
    int r = t - OFF_MERGE; int j = r >> 6, d = r & 63;
    ws[t] = p.w_merge[d * 224 + j];
  } else if (t < OFF_COMB) {
    int r = t - OFF_STATS; int j = r >> 6, d = r & 63;
    ws[t] = p.w_stats[d * 383 + j];
  } else if (t < OFF_H2TWO) {
    int r = t - OFF_COMB; int j = r >> 8, d = r & 255;
    ws[t] = p.w_comb[d * 224 + j];
  } else if (t < OFF_T2HWO) {
    int r = t - OFF_H2TWO; int e = r >> 5, d = r & 31;
    ws[t] = p.h2t_wout[d * 32 + e];
  } else {
    int r = t - OFF_T2HWO; int e = r >> 5, d = r & 31;
    ws[t] = p.t2h_wout[d * 32 + e];
  }
}

#define FMA4(acc, a4, w0, w1, w2, w3)                                   \
  acc.x += a4.x * w0.x + a4.y * w1.x + a4.z * w2.x + a4.w * w3.x;       \
  acc.y += a4.x * w0.y + a4.y * w1.y + a4.z * w2.y + a4.w * w3.y;       \
  acc.z += a4.x * w0.z + a4.y * w1.z + a4.z * w2.z + a4.w * w3.z;       \
  acc.w += a4.x * w0.w + a4.y * w1.w + a4.z * w2.w + a4.w * w3.w;

// launch_bounds 2nd arg measured as min BLOCKS/CU on this toolchain:
// (512,6)->VGPR cap 40 (spill), (512,3)->cap 84. LDS caps at 3 blocks/CU.
// Matvec stages i-tiled x4 in registers: ~50-60 live regs, no spill.
__global__ __launch_bounds__(TPB, 3) void enc_row(P p) {
  const int row = blockIdx.x;
  const int tid = threadIdx.x;
  const int lane = tid & 63, wq = tid >> 6;

  __shared__ float s_ht[165];  // hand_table region of obs
  __shared__ float sA[2560];   // hseq -> x(post-LN1) -> x2(post-LN2)
  __shared__ float sB[2560];   // enc K -> pre-LN1 -> ff[0:2560]
  __shared__ float sC[2560];   // enc V -> ff[2560:5120]
  __shared__ float sD[2624];   // enc Q^T (stride 41) -> attn O^T -> pre-LN2 (linear)
  __shared__ float s_om[64];   // masked-mean accum: h2t[0:32], t2h[32:64]
  __shared__ float s_sm[224];  // set_merged
  __shared__ float s_cb[256];  // combined (224 used; stats accumulated at 128..191)
  __shared__ int   s_cnt[2];   // hand count, table count

  const float* orow = p.obs + (size_t)row * 2988;
  const float* ws = p.ws;

  // ---- S1: stage + small set features + accum inits + presence counts ----
  if (tid < 165) s_ht[tid] = orow[tid];
  if (tid < 32) {
    float a = 0.f;
    for (int i = 0; i < 40; ++i) a += orow[i] * p.ce[i * 32 + tid];
    s_sm[tid] = a;                                     // hand_feat
  } else if (tid < 64) {
    int d = tid - 32; float a = 0.f;
    for (int i = 0; i < 40; ++i) a += orow[43 + i] * p.ce[i * 32 + d];
    s_sm[32 + d] = a;                                  // table_feat
  } else if (tid < 96) {
    int d = tid - 64; float a = 0.f;
    for (int i = 0; i < 40; ++i) a += orow[83 + i] * p.ce[i * 32 + d];
    s_sm[64 + d] = a;                                  // cap0_feat
  } else if (tid < 128) {
    int d = tid - 96; float a = 0.f;
    for (int i = 0; i < 40; ++i) a += orow[123 + i] * p.ce[i * 32 + d];
    s_sm[96 + d] = a;                                  // cap1_feat
  } else if (tid < 144) {
    int d = tid - 128;
    float a = p.bch[d];
    for (int j = 0; j < 3; ++j) a += orow[40 + j] * p.wch[d * 3 + j];
    s_sm[192 + d] = fmaxf(a, 0.f);                     // other_cnt_feat
  } else if (tid < 160) {
    int d = tid - 144;
    float a = p.bcc[d];
    for (int j = 0; j < 2; ++j) a += orow[163 + j] * p.wcc[d * 2 + j];
    s_sm[208 + d] = fmaxf(a, 0.f);                     // cap_cnt_feat
  }
  if (tid >= 192 && tid < 256) s_om[tid - 192] = 0.f;
  if (tid >= 256 && tid < 320) s_cb[128 + tid - 256] = p.b_stats[tid - 256];  // stats accum init
  if (tid == 320) {
    int c = 0; for (int i = 0; i < 40; ++i) c += (orow[i] > 0.5f);
    s_cnt[0] = c;
  } else if (tid == 321) {
    int c = 0; for (int i = 0; i < 40; ++i) c += (orow[43 + i] > 0.5f);
    s_cnt[1] = c;
  }
  __syncthreads();
  #define OB(i) s_ht[i]

  // ---- R3: card attn (640) + hseq proj (160, i-tile 4) + stats (96) ----
  for (int t = tid; t < 896; t += TPB) {
    if (t < 640) {
      int eh = t & 1, q = t >> 1;
      int a = q / 160, r = q - a * 160;
      int h = r / 40, i = r - h * 40;
      int qoff = a ? 43 : 0, koff = a ? 0 : 43;
      const float* Cq = ws + OFF_PE + a * 3840;
      const float* Ck = Cq + 1280;
      const float* Cv = Cq + 2560;
      const float* bin = a ? p.t2h_bin : p.h2t_bin;
      const int e0 = h * 8 + eh * 4;
      float qm = OB(qoff + i);
      float4 cq = *(const float4*)(Cq + i * 32 + e0);
      float4 bq = *(const float4*)(bin + e0);
      float4 bk = *(const float4*)(bin + 32 + e0);
      float q0 = qm * cq.x + bq.x, q1 = qm * cq.y + bq.y;
      float q2 = qm * cq.z + bq.z, q3 = qm * cq.w + bq.w;
      const float scale = 0.35355339059327373f;  // 1/sqrt(8)
      // pass 1: max only (km is pair-uniform -> shfl branch-safe)
      float mx = -1e30f;
      for (int j = 0; j < 40; ++j) {
        float km = OB(koff + j);
        float part = 0.f;
        if (km > 0.5f) {
          float4 ck = *(const float4*)(Ck + j * 32 + e0);
          part = q0 * (km * ck.x + bk.x) + q1 * (km * ck.y + bk.y)
               + q2 * (km * ck.z + bk.z) + q3 * (km * ck.w + bk.w);
        }
        float full = part + __shfl_xor(part, 1, 64);
        if (km > 0.5f) mx = fmaxf(mx, full * scale);
      }
      // pass 2: recompute dot, exp, denom, V-accumulate
      float den = 0.f;
      float o0 = 0.f, o1 = 0.f, o2 = 0.f, o3 = 0.f;
      for (int j = 0; j < 40; ++j) {
        float km = OB(koff + j);
        float part = 0.f;
        if (km > 0.5f) {
          float4 ck = *(const float4*)(Ck + j * 32 + e0);
          part = q0 * (km * ck.x + bk.x) + q1 * (km * ck.y + bk.y)
               + q2 * (km * ck.z + bk.z) + q3 * (km * ck.w + bk.w);
        }
        float full = part + __shfl_xor(part, 1, 64);
        if (km > 0.5f) {
          float pj = __expf(full * scale - mx);
          den += pj;
          float pk = pj * km;
          float4 cv = *(const float4*)(Cv + j * 32 + e0);
          o0 += pk * cv.x; o1 += pk * cv.y; o2 += pk * cv.z; o3 += pk * cv.w;
        }
      }
      float inv = 1.f / den;  // den==0 only if all keys masked; result gated by cnt later
      if (qm > 0.5f) {        // masked_mean sums only present queries
        float4 bv = *(const float4*)(bin + 64 + e0);
        atomicAdd(&s_om[a * 32 + e0 + 0], o0 * inv + bv.x);
        atomicAdd(&s_om[a * 32 + e0 + 1], o1 * inv + bv.y);
        atomicAdd(&s_om[a * 32 + e0 + 2], o2 * inv + bv.z);
        atomicAdd(&s_om[a * 32 + e0 + 3], o3 * inv + bv.w);
      }
    } else if (t < 800) {
      // hseq proj, i-tile 4: task (d0, ic) covers rows i0..i0+3, cols d0..d0+3
      int r = t - 640;
      int d0 = (r & 15) << 2, i0 = (r >> 4) << 2;
      const float* wt = ws + OFF_HPROJ + d0;
      float4 acc0 = *(const float4*)(ws + OFF_POSB + (i0 + 0) * 64 + d0);
      float4 acc1 = *(const float4*)(ws + OFF_POSB + (i0 + 1) * 64 + d0);
      float4 acc2 = *(const float4*)(ws + OFF_POSB + (i0 + 2) * 64 + d0);
      float4 acc3 = *(const float4*)(ws + OFF_POSB + (i0 + 3) * 64 + d0);
      const float* h0 = orow + 165 + (i0 + 0) * 61;
      const float* h1 = orow + 165 + (i0 + 1) * 61;
      const float* h2 = orow + 165 + (i0 + 2) * 61;
      const float* h3 = orow + 165 + (i0 + 3) * 61;
      for (int j = 0; j < 61; ++j) {
        float4 w = *(const float4*)(wt + j * 64);
        float a0 = h0[j], a1 = h1[j], a2 = h2[j], a3 = h3[j];
        acc0.x += a0 * w.x; acc0.y += a0 * w.y; acc0.z += a0 * w.z; acc0.w += a0 * w.w;
        acc1.x += a1 * w.x; acc1.y += a1 * w.y; acc1.z += a1 * w.z; acc1.w += a1 * w.w;
        acc2.x += a2 * w.x; acc2.y += a2 * w.y; acc2.z += a2 * w.z; acc2.w += a2 * w.w;
        acc3.x += a3 * w.x; acc3.y += a3 * w.y; acc3.z += a3 * w.z; acc3.w += a3 * w.w;
      }
      *(float4*)(sA + (i0 + 0) * 64 + d0) = acc0;
      *(float4*)(sA + (i0 + 1) * 64 + d0) = acc1;
      *(float4*)(sA + (i0 + 2) * 64 + d0) = acc2;
      *(float4*)(sA + (i0 + 3) * 64 + d0) = acc3;
    } else {
      // stats partial: chunk c covers j in [c*64, min(383, c*64+64))
      int r = t - 800;
      int c = r >> 4, d0 = (r & 15) << 2;
      int j0 = c * 64, j1 = (c == 5) ? 383 : j0 + 64;
      const float* st = orow + 2605;
      const float* wt = ws + OFF_STATS + d0;
      float x0 = 0.f, x1 = 0.f, x2 = 0.f, x3 = 0.f;
      for (int j = j0; j < j1; ++j) {
        float a0 = st[j];
        float4 w = *(const float4*)(wt + j * 64);
        x0 += a0 * w.x; x1 += a0 * w.y; x2 += a0 * w.z; x3 += a0 * w.w;
      }
      atomicAdd(&s_cb[128 + d0 + 0], x0);
      atomicAdd(&s_cb[128 + d0 + 1], x1);
      atomicAdd(&s_cb[128 + d0 + 2], x2);
      atomicAdd(&s_cb[128 + d0 + 3], x3);
    }
  }
  __syncthreads();

  // ---- R4: enc Q/K/V (480, i-tile 4 x d-tile 4) + attn-mean feats (16) ----
  for (int t = tid; t < 496; t += TPB) {
    if (t < 480) {
      int which = t / 160, r = t - which * 160;
      int d0 = (r & 15) << 2, i0 = (r >> 4) << 2;
      const float* wt = ws + (which == 0 ? OFF_ENCQ : (which == 1 ? OFF_ENCK : OFF_ENCV)) + d0;
      float4 bia = *(const float4*)(p.enc_bin + (which << 6) + d0);
      float4 acc0 = bia, acc1 = bia, acc2 = bia, acc3 = bia;
      const float* a0p = sA + (i0 + 0) * 64;
      const float* a1p = sA + (i0 + 1) * 64;
      const float* a2p = sA + (i0 + 2) * 64;
      const float* a3p = sA + (i0 + 3) * 64;
      for (int j = 0; j < 64; j += 4) {
        float4 w0 = *(const float4*)(wt + (j + 0) * 64);
        float4 w1 = *(const float4*)(wt + (j + 1) * 64);
        float4 w2 = *(const float4*)(wt + (j + 2) * 64);
        float4 w3 = *(const float4*)(wt + (j + 3) * 64);
        float4 a4;
        a4 = *(const float4*)(a0p + j); FMA4(acc0, a4, w0, w1, w2, w3);
        a4 = *(const float4*)(a1p + j); FMA4(acc1, a4, w0, w1, w2, w3);
        a4 = *(const float4*)(a2p + j); FMA4(acc2, a4, w0, w1, w2, w3);
        a4 = *(const float4*)(a3p + j); FMA4(acc3, a4, w0, w1, w2, w3);
      }
      if (which == 0) {       // Q^T, stride 41
        sD[(d0 + 0) * 41 + i0 + 0] = acc0.x; sD[(d0 + 1) * 41 + i0 + 0] = acc0.y;
        sD[(d0 + 2) * 41 + i0 + 0] = acc0.z; sD[(d0 + 3) * 41 + i0 + 0] = acc0.w;
        sD[(d0 + 0) * 41 + i0 + 1] = acc1.x; sD[(d0 + 1) * 41 + i0 + 1] = acc1.y;
        sD[(d0 + 2) * 41 + i0 + 1] = acc1.z; sD[(d0 + 3) * 41 + i0 + 1] = acc1.w;
        sD[(d0 + 0) * 41 + i0 + 2] = acc2.x; sD[(d0 + 1) * 41 + i0 + 2] = acc2.y;
        sD[(d0 + 2) * 41 + i0 + 2] = acc2.z; sD[(d0 + 3) * 41 + i0 + 2] = acc2.w;
        sD[(d0 + 0) * 41 + i0 + 3] = acc3.x; sD[(d0 + 1) * 41 + i0 + 3] = acc3.y;
        sD[(d0 + 2) * 41 + i0 + 3] = acc3.z; sD[(d0 + 3) * 41 + i0 + 3] = acc3.w;
      } else {
        float* dst = (which == 1) ? sB : sC;
        *(float4*)(dst + (i0 + 0) * 64 + d0) = acc0;
        *(float4*)(dst + (i0 + 1) * 64 + d0) = acc1;
        *(float4*)(dst + (i0 + 2) * 64 + d0) = acc2;
        *(float4*)(dst + (i0 + 3) * 64 + d0) = acc3;
      }
    } else {
      int r = t - 480;
      int a = r >> 3, d0 = (r & 7) << 2;
      int ch = s_cnt[0], ct = s_cnt[1];
      float4 v = make_float4(0.f, 0.f, 0.f, 0.f);
      if (ch > 0 && ct > 0) {
        float ic = 1.f / (float)(a ? ct : ch);
        const float* wt = ws + (a ? OFF_T2HWO : OFF_H2TWO) + d0;
        const float* om = s_om + a * 32;
        v = *(const float4*)((a ? p.t2h_bout : p.h2t_bout) + d0);
        for (int e = 0; e < 32; ++e) {
          float oe = om[e] * ic;
          float4 w = *(const float4*)(wt + e * 32);
          v.x += oe * w.x; v.y += oe * w.y; v.z += oe * w.z; v.w += oe * w.w;
        }
      }
      *(float4*)(s_sm + 128 + a * 32 + d0) = v;
    }
  }
  __syncthreads();

  // ---- R5: encoder attention (320 pair-split, recompute-dot softmax) + set_feat ----
  if (tid < 320) {
    int eh = tid & 1, q = tid >> 1;
    int h = q / 40, i = q - h * 40;
    const int e0 = h * 16 + eh * 8;
    float q8[8];
    #pragma unroll
    for (int e = 0; e < 8; ++e) q8[e] = sD[(e0 + e) * 41 + i];
    float mx = -1e30f;
    for (int j = 0; j < 40; ++j) {
      const float* kr = sB + (j << 6) + e0;
      float4 k0 = *(const float4*)kr;
      float4 k1 = *(const float4*)(kr + 4);
      float part = q8[0] * k0.x + q8[1] * k0.y + q8[2] * k0.z + q8[3] * k0.w
                 + q8[4] * k1.x + q8[5] * k1.y + q8[6] * k1.z + q8[7] * k1.w;
      float s = (part + __shfl_xor(part, 1, 64)) * 0.25f;  // 1/sqrt(16)
      mx = fmaxf(mx, s);
    }
    float den = 0.f;
    float o8[8];
    #pragma unroll
    for (int e = 0; e < 8; ++e) o8[e] = 0.f;
    for (int j = 0; j < 40; ++j) {
      const float* kr = sB + (j << 6) + e0;
      float4 k0 = *(const float4*)kr;
      float4 k1 = *(const float4*)(kr + 4);
      float part = q8[0] * k0.x + q8[1] * k0.y + q8[2] * k0.z + q8[3] * k0.w
                 + q8[4] * k1.x + q8[5] * k1.y + q8[6] * k1.z + q8[7] * k1.w;
      float s = (part + __shfl_xor(part, 1, 64)) * 0.25f;
      float pj = __expf(s - mx);
      den += pj;
      const float* vr = sC + (j << 6) + e0;
      float4 v0 = *(const float4*)vr;
      float4 v1 = *(const float4*)(vr + 4);
      o8[0] += pj * v0.x; o8[1] += pj * v0.y; o8[2] += pj * v0.z; o8[3] += pj * v0.w;
      o8[4] += pj * v1.x; o8[5] += pj * v1.y; o8[6] += pj * v1.z; o8[7] += pj * v1.w;
    }
    float inv = 1.f / den;
    #pragma unroll
    for (int e = 0; e < 8; ++e) sD[(e0 + e) * 41 + i] = o8[e] * inv;  // O^T, own slots
  } else if (tid < 336) {
    int d0 = (tid - 320) << 2;
    const float* wt = ws + OFF_MERGE + d0;
    float4 acc = *(const float4*)(p.b_merge + d0);
    for (int j = 0; j < 224; j += 4) {
      float4 a4 = *(const float4*)(s_sm + j);
      float4 w0 = *(const float4*)(wt + j * 64);
      float4 w1 = *(const float4*)(wt + (j + 1) * 64);
      float4 w2 = *(const float4*)(wt + (j + 2) * 64);
      float4 w3 = *(const float4*)(wt + (j + 3) * 64);
      FMA4(acc, a4, w0, w1, w2, w3);
    }
    acc.x = fmaxf(acc.x, 0.f); acc.y = fmaxf(acc.y, 0.f);
    acc.z = fmaxf(acc.z, 0.f); acc.w = fmaxf(acc.w, 0.f);
    *(float4*)(s_cb + d0) = acc;                       // set_feat
  }
  __syncthreads();

  // ---- R6: attn out-proj + residual -> pre-LN1 (160, i-tile 4 x d-tile 4) ----
  for (int t = tid; t < 160; t += TPB) {
    int d0 = (t & 15) << 2, i0 = (t >> 4) << 2;
    const float* wt = ws + OFF_ENCOUT + d0;
    float4 bo = *(const float4*)(p.enc_bout + d0);
    float4 acc0 = *(const float4*)(sA + (i0 + 0) * 64 + d0);
    float4 acc1 = *(const float4*)(sA + (i0 + 1) * 64 + d0);
    float4 acc2 = *(const float4*)(sA + (i0 + 2) * 64 + d0);
    float4 acc3 = *(const float4*)(sA + (i0 + 3) * 64 + d0);
    acc0.x += bo.x; acc0.y += bo.y; acc0.z += bo.z; acc0.w += bo.w;
    acc1.x += bo.x; acc1.y += bo.y; acc1.z += bo.z; acc1.w += bo.w;
    acc2.x += bo.x; acc2.y += bo.y; acc2.z += bo.z; acc2.w += bo.w;
    acc3.x += bo.x; acc3.y += bo.y; acc3.z += bo.z; acc3.w += bo.w;
    for (int j = 0; j < 64; ++j) {
      float4 w = *(const float4*)(wt + j * 64);
      const float* oc = sD + j * 41 + i0;
      float a0 = oc[0], a1 = oc[1], a2 = oc[2], a3 = oc[3];
      acc0.x += a0 * w.x; acc0.y += a0 * w.y; acc0.z += a0 * w.z; acc0.w += a0 * w.w;
      acc1.x += a1 * w.x; acc1.y += a1 * w.y; acc1.z += a1 * w.z; acc1.w += a1 * w.w;
      acc2.x += a2 * w.x; acc2.y += a2 * w.y; acc2.z += a2 * w.z; acc2.w += a2 * w.w;
      acc3.x += a3 * w.x; acc3.y += a3 * w.y; acc3.z += a3 * w.z; acc3.w += a3 * w.w;
    }
    *(float4*)(sB + (i0 + 0) * 64 + d0) = acc0;
    *(float4*)(sB + (i0 + 1) * 64 + d0) = acc1;
    *(float4*)(sB + (i0 + 2) * 64 + d0) = acc2;
    *(float4*)(sB + (i0 + 3) * 64 + d0) = acc3;
  }
  __syncthreads();

  // ---- R7: LN1 (wave-parallel) -> sA ----
  {
    float g = p.ln1_g[lane], b = p.ln1_b[lane];
    for (int i = wq; i < 40; i += 8) {
      float x = sB[(i << 6) + lane];
      float s = x;
      #pragma unroll
      for (int off = 32; off; off >>= 1) s += __shfl_xor(s, off, 64);
      float m = s * 0.015625f;
      float xm = x - m;
      float v = xm * xm;
      #pragma unroll
      for (int off = 32; off; off >>= 1) v += __shfl_xor(v, off, 64);
      float rs = rsqrtf(v * 0.015625f + 1e-5f);
      sA[(i << 6) + lane] = xm * rs * g + b;
    }
  }
  __syncthreads();

  // ---- R8: FF1 (relu) (320, i-tile 4 x f-tile 4) -> sB|sC ----
  for (int t = tid; t < 320; t += TPB) {
    int f0 = (t & 31) << 2, i0 = (t >> 5) << 2;
    const float* wt = ws + OFF_FF1 + f0;
    float4 bia = *(const float4*)(p.b_ff1 + f0);
    float4 acc0 = bia, acc1 = bia, acc2 = bia, acc3 = bia;
    const float* a0p = sA + (i0 + 0) * 64;
    const float* a1p = sA + (i0 + 1) * 64;
    const float* a2p = sA + (i0 + 2) * 64;
    const float* a3p = sA + (i0 + 3) * 64;
    for (int j = 0; j < 64; j += 4) {
      float4 w0 = *(const float4*)(wt + (j + 0) * 128);
      float4 w1 = *(const float4*)(wt + (j + 1) * 128);
      float4 w2 = *(const float4*)(wt + (j + 2) * 128);
      float4 w3 = *(const float4*)(wt + (j + 3) * 128);
      float4 a4;
      a4 = *(const float4*)(a0p + j); FMA4(acc0, a4, w0, w1, w2, w3);
      a4 = *(const float4*)(a1p + j); FMA4(acc1, a4, w0, w1, w2, w3);
      a4 = *(const float4*)(a2p + j); FMA4(acc2, a4, w0, w1, w2, w3);
      a4 = *(const float4*)(a3p + j); FMA4(acc3, a4, w0, w1, w2, w3);
    }
    acc0.x = fmaxf(acc0.x, 0.f); acc0.y = fmaxf(acc0.y, 0.f);
    acc0.z = fmaxf(acc0.z, 0.f); acc0.w = fmaxf(acc0.w, 0.f);
    acc1.x = fmaxf(acc1.x, 0.f); acc1.y = fmaxf(acc1.y, 0.f);
    acc1.z = fmaxf(acc1.z, 0.f); acc1.w = fmaxf(acc1.w, 0.f);
    acc2.x = fmaxf(acc2.x, 0.f); acc2.y = fmaxf(acc2.y, 0.f);
    acc2.z = fmaxf(acc2.z, 0.f); acc2.w = fmaxf(acc2.w, 0.f);
    acc3.x = fmaxf(acc3.x, 0.f); acc3.y = fmaxf(acc3.y, 0.f);
    acc3.z = fmaxf(acc3.z, 0.f); acc3.w = fmaxf(acc3.w, 0.f);
    float* d0p = (i0 + 0 < 20) ? (sB + (i0 + 0) * 128) : (sC + (i0 + 0 - 20) * 128);
    float* d1p = (i0 + 1 < 20) ? (sB + (i0 + 1) * 128) : (sC + (i0 + 1 - 20) * 128);
    float* d2p = (i0 + 2 < 20) ? (sB + (i0 + 2) * 128) : (sC + (i0 + 2 - 20) * 128);
    float* d3p = (i0 + 3 < 20) ? (sB + (i0 + 3) * 128) : (sC + (i0 + 3 - 20) * 128);
    *(float4*)(d0p + f0) = acc0;
    *(float4*)(d1p + f0) = acc1;
    *(float4*)(d2p + f0) = acc2;
    *(float4*)(d3p + f0) = acc3;
  }
  __syncthreads();

  // ---- R9: FF2 + residual -> pre-LN2 (320, i-tile 2 x d-tile 4) ----
  for (int t = tid; t < 320; t += TPB) {
    int d0 = (t & 15) << 2, i0 = (t >> 4) << 1;
    const float* wt = ws + OFF_FF2 + d0;
    float4 bb = *(const float4*)(p.b_ff2 + d0);
    float4 acc0 = *(const float4*)(sA + (i0 + 0) * 64 + d0);
    float4 acc1 = *(const float4*)(sA + (i0 + 1) * 64 + d0);
    acc0.x += bb.x; acc0.y += bb.y; acc0.z += bb.z; acc0.w += bb.w;
    acc1.x += bb.x; acc1.y += bb.y; acc1.z += bb.z; acc1.w += bb.w;
    const float* F0 = (i0 + 0 < 20) ? (sB + (i0 + 0) * 128) : (sC + (i0 + 0 - 20) * 128);
    const float* F1 = (i0 + 1 < 20) ? (sB + (i0 + 1) * 128) : (sC + (i0 + 1 - 20) * 128);
    for (int f = 0; f < 128; f += 4) {
      float4 w0 = *(const float4*)(wt + (f + 0) * 64);
      float4 w1 = *(const float4*)(wt + (f + 1) * 64);
      float4 w2 = *(const float4*)(wt + (f + 2) * 64);
      float4 w3 = *(const float4*)(wt + (f + 3) * 64);
      float4 a4;
      a4 = *(const float4*)(F0 + f); FMA4(acc0, a4, w0, w1, w2, w3);
      a4 = *(const float4*)(F1 + f); FMA4(acc1, a4, w0, w1, w2, w3);
    }
    *(float4*)(sD + (i0 + 0) * 64 + d0) = acc0;
    *(float4*)(sD + (i0 + 1) * 64 + d0) = acc1;
  }
  __syncthreads();

  // ---- R10: LN2 (wave-parallel) -> sA ----
  {
    float g = p.ln2_g[lane], b = p.ln2_b[lane];
    for (int i = wq; i < 40; i += 8) {
      float x = sD[(i << 6) + lane];
      float s = x;
      #pragma unroll
      for (int off = 32; off; off >>= 1) s += __shfl_xor(s, off, 64);
      float m = s * 0.015625f;
      float xm = x - m;
      float v = xm * xm;
      #pragma unroll
      for (int off = 32; off; off >>= 1) v += __shfl_xor(v, off, 64);
      float rs = rsqrtf(v * 0.015625f + 1e-5f);
      sA[(i << 6) + lane] = xm * rs * g + b;
    }
  }
  __syncthreads();

  // ---- R11: hist mean + stats relu + seat_feat ----
  if (tid < 64) {
    float a = 0.f;
    for (int i = 0; i < 40; ++i) a += sA[(i << 6) + tid];
    s_cb[64 + tid] = a * 0.025f;                       // hist_feat
    s_cb[128 + tid] = fmaxf(s_cb[128 + tid], 0.f);     // stats relu (accumulated in R3)
  } else if (tid < 96) {
    int d = tid - 64;
    const float* sv = p.seat + (size_t)row * 6;
    float acc = p.b_seat[d];
    for (int j = 0; j < 6; ++j) acc += sv[j] * p.w_seat[d * 6 + j];
    s_cb[192 + d] = fmaxf(acc, 0.f);                   // seat_feat
  }
  __syncthreads();

  // ---- R12: final 224 -> 256 matvec + relu ----
  if (tid < 256) {
    const float* wt = ws + OFF_COMB + tid;
    float acc = p.b_comb[tid];
    for (int j = 0; j < 224; j += 4) {
      float4 a4 = *(const float4*)(s_cb + j);
      acc += a4.x * wt[j * 256] + a4.y * wt[(j + 1) * 256]
           + a4.z * wt[(j + 2) * 256] + a4.w * wt[(j + 3) * 256];
    }
    p.out[(size_t)row * 256 + tid] = fmaxf(acc, 0.f);
  }
  #undef OB
}

extern "C" void kernel_launch(void* const* d_in, const int* in_sizes, int n_in,
                              void* d_out, int out_size, void* d_ws, size_t ws_size,
                              hipStream_t stream) {
  typedef const float* F;
  P p;
  p.obs      = (F)d_in[0];
  p.seat     = (F)d_in[1];
  p.ce       = (F)d_in[2];
  p.wch      = (F)d_in[3];
  p.bch      = (F)d_in[4];
  p.wcc      = (F)d_in[5];
  p.bcc      = (F)d_in[6];
  p.h2t_win  = (F)d_in[7];
  p.h2t_bin  = (F)d_in[8];
  p.h2t_wout = (F)d_in[9];
  p.h2t_bout = (F)d_in[10];
  p.t2h_win  = (F)d_in[11];
  p.t2h_bin  = (F)d_in[12];
  p.t2h_wout = (F)d_in[13];
  p.t2h_bout = (F)d_in[14];
  p.w_merge  = (F)d_in[15];
  p.b_merge  = (F)d_in[16];
  p.w_hproj  = (F)d_in[17];
  p.b_hproj  = (F)d_in[18];
  p.pos      = (F)d_in[19];
  p.enc_win  = (F)d_in[20];
  p.enc_bin  = (F)d_in[21];
  p.enc_wout = (F)d_in[22];
  p.enc_bout = (F)d_in[23];
  p.ln1_g    = (F)d_in[24];
  p.ln1_b    = (F)d_in[25];
  p.w_ff1    = (F)d_in[26];
  p.b_ff1    = (F)d_in[27];
  p.w_ff2    = (F)d_in[28];
  p.b_ff2    = (F)d_in[29];
  p.ln2_g    = (F)d_in[30];
  p.ln2_b    = (F)d_in[31];
  p.w_stats  = (F)d_in[32];
  p.b_stats  = (F)d_in[33];
  p.w_seat   = (F)d_in[34];
  p.b_seat   = (F)d_in[35];
  p.w_comb   = (F)d_in[36];
  p.b_comb   = (F)d_in[37];
  p.ws  = (const float*)d_ws;
  p.out = (float*)d_out;

  const int Bn = in_sizes[0] / 2988;
  hipLaunchKernelGGL(prep_kernel, dim3((WS_TOTAL + 255) / 256), dim3(256), 0, stream,
                     p, (float*)d_ws);
  hipLaunchKernelGGL(enc_row, dim3(Bn), dim3(TPB), 0, stream, p);
}